// Round 6
// baseline (95.138 us; speedup 1.0000x reference)
//
#include <hip/hip_runtime.h>

typedef _Float16 f16;
typedef _Float16 f16x8 __attribute__((ext_vector_type(8)));
typedef _Float16 f16x4 __attribute__((ext_vector_type(4)));
typedef _Float16 f16x2 __attribute__((ext_vector_type(2)));
typedef float f32x4 __attribute__((ext_vector_type(4)));
typedef float f32x16 __attribute__((ext_vector_type(16)));

#define MDIM 128
#define NDIM 256
#define CDIM 256
#define ROWS (MDIM*NDIM)   // 32768
#define L2E 1.4426950408889634f

// pack two f32 -> f16x2 in one int
__device__ inline int pk2(float a, float b) {
  union { f16x2 h; int i; } u;
  u.h[0] = (f16)a; u.h[1] = (f16)b;
  return u.i;
}

// ---------------- K0: weight prepack (LDS-transpose tiles) ----------------
// wq/wk/wv -> f16 [je][k], je=h*32+c (orig col j=(je&31)*8+(je>>5)); 1/sqrt(32)
// folded into wq. wf -> f16 [col][ke], ke row-permuted the same way.
__global__ __launch_bounds__(256) void k_prep(
    const float* __restrict__ wq, const float* __restrict__ wk,
    const float* __restrict__ wv, const float* __restrict__ wf,
    f16* __restrict__ bq, f16* __restrict__ bk, f16* __restrict__ bv,
    f16* __restrict__ bw)
{
  __shared__ f16 ld[64][264];
  int which = blockIdx.x >> 2, kb = blockIdx.x & 3;
  int t = threadIdx.x;
  int k0 = kb * 64;
  if (which < 3) {
    const float* W = which == 0 ? wq : which == 1 ? wk : wv;
    f16* dst       = which == 0 ? bq : which == 1 ? bk : bv;
    float sc = which == 0 ? 0.17677669529663689f : 1.0f;
    for (int r = 0; r < 64; ++r)
      ld[r][t] = (f16)(W[(size_t)(k0 + r) * 256 + t] * sc);
    __syncthreads();
    int j = (t & 31) * 8 + (t >> 5);
#pragma unroll
    for (int rr = 0; rr < 8; ++rr) {
      f16x8 o;
#pragma unroll
      for (int i = 0; i < 8; ++i) o[i] = ld[rr * 8 + i][j];
      *(f16x8*)(dst + (size_t)t * 256 + k0 + rr * 8) = o;
    }
  } else {
    for (int r = 0; r < 64; ++r) {
      int ke = k0 + r;
      int jr = (ke & 31) * 8 + (ke >> 5);
      ld[r][t] = (f16)wf[(size_t)jr * 256 + t];
    }
    __syncthreads();
#pragma unroll
    for (int rr = 0; rr < 8; ++rr) {
      f16x8 o;
#pragma unroll
      for (int i = 0; i < 8; ++i) o[i] = ld[rr * 8 + i][t];
      *(f16x8*)(bw + (size_t)t * 256 + k0 + rr * 8) = o;
    }
  }
}

// ---------------- K1: fused LayerNorm + QKV GEMM (no-Bs, 1 barrier) --------
// 512 thr / 8 waves per 64-row block. LN -> As once; then each wave computes
// a 64x48 output strip twice (16 strips cover 768 cols). B-fragments load
// DIRECTLY from prepacked L2-resident weights (layout == fragment layout).
// V strips transpose via per-wave LDS buffers (wave-local, no barrier).
__global__ __launch_bounds__(512) void k_lnqkv(const float* __restrict__ x,
    const float* __restrict__ g, const float* __restrict__ bb,
    const f16* __restrict__ bq, const f16* __restrict__ bk, const f16* __restrict__ bv,
    f16* __restrict__ qo, f16* __restrict__ ko, f16* __restrict__ vT)
{
  __shared__ f16 As[64][264];        // 33.8 KB
  __shared__ f16 vtmp[8][16][72];    // 18 KB, per-wave transpose buffers
  int bm = blockIdx.x;
  int t = threadIdx.x, lane = t & 63, w = t >> 6;   // w in 0..7
  int l15 = lane & 15, l4 = lane >> 4;
  // --- LN: wave w -> rows w*8 .. w*8+7 ---
  const float4 gv  = *(const float4*)(g + lane * 4);
  const float4 bv4 = *(const float4*)(bb + lane * 4);
#pragma unroll
  for (int rr = 0; rr < 8; ++rr) {
    int r = w * 8 + rr;
    const float4 xv = *(const float4*)(x + (size_t)(bm * 64 + r) * 256 + lane * 4);
    float s  = xv.x + xv.y + xv.z + xv.w;
    float s2 = xv.x*xv.x + xv.y*xv.y + xv.z*xv.z + xv.w*xv.w;
#pragma unroll
    for (int mm = 1; mm < 64; mm <<= 1) {
      s  += __shfl_xor(s,  mm, 64);
      s2 += __shfl_xor(s2, mm, 64);
    }
    float mu  = s * (1.0f / 256.0f);
    float var = s2 * (1.0f / 256.0f) - mu * mu;
    float rs  = rsqrtf(var + 1e-5f);
    f16x4 ov;
    ov[0] = (f16)((xv.x - mu) * rs * gv.x + bv4.x);
    ov[1] = (f16)((xv.y - mu) * rs * gv.y + bv4.y);
    ov[2] = (f16)((xv.z - mu) * rs * gv.z + bv4.z);
    ov[3] = (f16)((xv.w - mu) * rs * gv.w + bv4.w);
    *(f16x4*)&As[r][lane * 4] = ov;
  }
  __syncthreads();   // the ONLY block-wide barrier
  // --- 2 iterations x (64 rows x 48 cols) per wave ---
  for (int it = 0; it < 2; ++it) {
    int gc0 = it * 384 + w * 48;
    f32x4 acc[4][3] = {};
#pragma unroll
    for (int kt = 0; kt < 8; ++kt) {
      f16x8 af[4];
#pragma unroll
      for (int mi = 0; mi < 4; ++mi)
        af[mi] = *(const f16x8*)&As[mi * 16 + l15][kt * 32 + l4 * 8];
#pragma unroll
      for (int ni = 0; ni < 3; ++ni) {
        int gc = gc0 + ni * 16;
        const f16* B = gc < 256 ? bq : gc < 512 ? bk : bv;
        f16x8 bf = *(const f16x8*)(B + (size_t)((gc & 255) + l15) * 256 + kt * 32 + l4 * 8);
#pragma unroll
        for (int mi = 0; mi < 4; ++mi)
          acc[mi][ni] = __builtin_amdgcn_mfma_f32_16x16x32_f16(af[mi], bf, acc[mi][ni], 0, 0, 0);
      }
    }
#pragma unroll
    for (int ni = 0; ni < 3; ++ni) {
      int gc = gc0 + ni * 16;
      if (gc < 512) {
        f16* dst = gc < 256 ? qo : ko;
        int col = (gc & 255) + l15;
#pragma unroll
        for (int mi = 0; mi < 4; ++mi)
#pragma unroll
          for (int r = 0; r < 4; ++r)
            dst[(size_t)(bm * 64 + mi * 16 + l4 * 4 + r) * 256 + col] = (f16)acc[mi][ni][r];
      } else {
        // V: transpose 16ch x 64n through wave-private vtmp (no barrier)
#pragma unroll
        for (int mi = 0; mi < 4; ++mi)
#pragma unroll
          for (int r = 0; r < 4; ++r)
            vtmp[w][l15][mi * 16 + l4 * 4 + r] = (f16)acc[mi][ni][r];
        int ch = lane >> 2, nq = (lane & 3) * 16;
        f16x8 v0 = *(const f16x8*)&vtmp[w][ch][nq];
        f16x8 v1 = *(const f16x8*)&vtmp[w][ch][nq + 8];
        size_t gdst = ((size_t)(bm >> 2) * 256 + (gc & 255) + ch) * 256 + (bm & 3) * 64 + nq;
        *(f16x8*)(vT + gdst)     = v0;
        *(f16x8*)(vT + gdst + 8) = v1;
      }
    }
  }
}

// ---------------- K2: attention (block = (m,h), 8 waves x 32 queries) ------
__global__ __launch_bounds__(512, 4) void k_attn(const f16* __restrict__ q,
    const f16* __restrict__ k, const f16* __restrict__ vT, f16* __restrict__ o)
{
  __shared__ f16 ks[256][40];
  __shared__ f16 vt[32][264];
  int bx = blockIdx.x;
  int m = bx >> 3, h = bx & 7;
  int t = threadIdx.x, lane = t & 63, w = t >> 6;
  int i32 = lane & 31, hi = lane >> 5;
  size_t rowbase = (size_t)m * 256;
#pragma unroll
  for (int p = 0; p < 2; ++p) {
    int n = p * 128 + (t >> 2);
    int c0 = (t & 3) * 8;
    *(f16x8*)&ks[n][c0] = *(const f16x8*)(k + (rowbase + n) * 256 + h * 32 + c0);
  }
#pragma unroll
  for (int p = 0; p < 2; ++p) {
    int idx = p * 512 + t;
    int c = idx >> 5, nb = (idx & 31) * 8;
    *(f16x8*)&vt[c][nb] = *(const f16x8*)(vT + ((size_t)m * 256 + h * 32 + c) * 256 + nb);
  }
  __syncthreads();
  int qi0 = w * 32;
  const f16* qp = q + (rowbase + qi0 + i32) * 256 + h * 32 + hi * 8;
  f16x8 qf0 = *(const f16x8*)(qp);
  f16x8 qf1 = *(const f16x8*)(qp + 16);
  f32x16 O = {};
  float m_run = -1e30f, l_run = 0.f;
#pragma unroll 2
  for (int kb = 0; kb < 8; ++kb) {
    f16x8 kf0 = *(const f16x8*)&ks[kb * 32 + i32][hi * 8];
    f16x8 kf1 = *(const f16x8*)&ks[kb * 32 + i32][16 + hi * 8];
    f32x16 s = {};
    __builtin_amdgcn_s_setprio(1);
    s = __builtin_amdgcn_mfma_f32_32x32x16_f16(kf0, qf0, s, 0, 0, 0);
    s = __builtin_amdgcn_mfma_f32_32x32x16_f16(kf1, qf1, s, 0, 0, 0);
    __builtin_amdgcn_s_setprio(0);
#pragma unroll
    for (int r = 0; r < 16; ++r) s[r] *= L2E;
    float pmax = s[0];
#pragma unroll
    for (int r = 1; r < 16; ++r) pmax = fmaxf(pmax, s[r]);
    pmax = fmaxf(pmax, __shfl_xor(pmax, 32, 64));
    if (!__all(pmax - m_run <= 8.f)) {
      float m_new = fmaxf(m_run, pmax);
      float f = __builtin_amdgcn_exp2f(m_run - m_new);
      l_run *= f;
#pragma unroll
      for (int r = 0; r < 16; ++r)
        O[r] *= __shfl(f, (r & 3) + 8 * (r >> 2) + 4 * hi, 64);
      m_run = m_new;
    }
    float lsum = 0.f;
#pragma unroll
    for (int r = 0; r < 16; ++r) {
      float e = __builtin_amdgcn_exp2f(s[r] - m_run);
      s[r] = e;
      lsum += e;
    }
    lsum += __shfl_xor(lsum, 32, 64);
    l_run += lsum;
    int W0[4], W1[4];
#pragma unroll
    for (int qq = 0; qq < 4; ++qq) {
      W0[qq] = pk2(s[4 * qq],     s[4 * qq + 1]);
      W1[qq] = pk2(s[4 * qq + 2], s[4 * qq + 3]);
    }
#pragma unroll
    for (int ks2 = 0; ks2 < 2; ++ks2) {
      int X0 = W0[2 * ks2], Y0 = W0[2 * ks2 + 1];
      int X1 = W1[2 * ks2], Y1 = W1[2 * ks2 + 1];
      int a0 = __shfl(X0, i32, 64),      b0 = __shfl(Y0, i32, 64);
      int a1 = __shfl(X1, i32, 64),      b1 = __shfl(Y1, i32, 64);
      int a2 = __shfl(X0, i32 + 32, 64), b2 = __shfl(Y0, i32 + 32, 64);
      int a3 = __shfl(X1, i32 + 32, 64), b3 = __shfl(Y1, i32 + 32, 64);
      union { unsigned int ww[4]; f16x8 v; } pa;
      pa.ww[0] = hi ? (unsigned)b0 : (unsigned)a0;
      pa.ww[1] = hi ? (unsigned)b1 : (unsigned)a1;
      pa.ww[2] = hi ? (unsigned)b2 : (unsigned)a2;
      pa.ww[3] = hi ? (unsigned)b3 : (unsigned)a3;
      f16x8 vb = *(const f16x8*)&vt[i32][kb * 32 + ks2 * 16 + hi * 8];
      __builtin_amdgcn_s_setprio(1);
      O = __builtin_amdgcn_mfma_f32_32x32x16_f16(pa.v, vb, O, 0, 0, 0);
      __builtin_amdgcn_s_setprio(0);
    }
  }
  float inv = 1.f / l_run;
#pragma unroll
  for (int r = 0; r < 16; ++r) {
    int i = (r & 3) + 8 * (r >> 2) + 4 * hi;
    float fr = __shfl(inv, i, 64);
    o[(rowbase + (size_t)(qi0 + i)) * 256 + h * 32 + i32] = (f16)(O[r] * fr);
  }
}

// ---------------- K3: output projection (no-Bs, 1 barrier) ----------------
// 512 thr / 8 waves per 64-row block; wave w owns cols w*32..w*32+31;
// B-fragments direct from prepacked bw (L2-resident).
__global__ __launch_bounds__(512) void k_out(const f16* __restrict__ a,
    const f16* __restrict__ bw, const float* __restrict__ bias,
    float* __restrict__ out)
{
  __shared__ f16 As[64][264];
  int bm = blockIdx.x;
  int t = threadIdx.x, lane = t & 63, w = t >> 6;
  int l15 = lane & 15, l4 = lane >> 4;
#pragma unroll
  for (int p = 0; p < 4; ++p) {
    int idx = p * 512 + t;
    int r = idx >> 5, c0 = (idx & 31) * 8;
    *(f16x8*)&As[r][c0] = *(const f16x8*)(a + (size_t)(bm * 64 + r) * 256 + c0);
  }
  __syncthreads();
  int gc0 = w * 32;
  f32x4 acc[4][2] = {};
#pragma unroll
  for (int kt = 0; kt < 8; ++kt) {
    f16x8 af[4];
#pragma unroll
    for (int mi = 0; mi < 4; ++mi)
      af[mi] = *(const f16x8*)&As[mi * 16 + l15][kt * 32 + l4 * 8];
#pragma unroll
    for (int ni = 0; ni < 2; ++ni) {
      f16x8 bf = *(const f16x8*)(bw + (size_t)(gc0 + ni * 16 + l15) * 256 + kt * 32 + l4 * 8);
#pragma unroll
      for (int mi = 0; mi < 4; ++mi)
        acc[mi][ni] = __builtin_amdgcn_mfma_f32_16x16x32_f16(af[mi], bf, acc[mi][ni], 0, 0, 0);
    }
  }
  float b0 = bias[gc0 + l15], b1 = bias[gc0 + 16 + l15];
#pragma unroll
  for (int mi = 0; mi < 4; ++mi)
#pragma unroll
    for (int r = 0; r < 4; ++r) {
      int row = bm * 64 + mi * 16 + l4 * 4 + r;
      out[(size_t)row * 256 + gc0 + l15]      = acc[mi][0][r] + b0;
      out[(size_t)row * 256 + gc0 + 16 + l15] = acc[mi][1][r] + b1;
    }
}

extern "C" void kernel_launch(void* const* d_in, const int* in_sizes, int n_in,
                              void* d_out, int out_size, void* d_ws, size_t ws_size,
                              hipStream_t stream)
{
  const float* x  = (const float*)d_in[0];
  const float* g  = (const float*)d_in[1];
  const float* b  = (const float*)d_in[2];
  const float* wq = (const float*)d_in[3];
  const float* wk = (const float*)d_in[4];
  const float* wv = (const float*)d_in[5];
  const float* wf = (const float*)d_in[6];
  const float* bf = (const float*)d_in[7];
  float* out = (float*)d_out;

  char* ws = (char*)d_ws;
  f16* ah  = (f16*)(ws);                                 // attn output
  f16* qh  = (f16*)(ws + (size_t)16 * 1024 * 1024);
  f16* kh  = (f16*)(ws + (size_t)32 * 1024 * 1024);
  f16* vTh = (f16*)(ws + (size_t)48 * 1024 * 1024);      // [m][ch][n]
  char* wbase = ws + (size_t)64 * 1024 * 1024;
  f16* bq = (f16*)(wbase);
  f16* bk = (f16*)(wbase + 128 * 1024);
  f16* bv = (f16*)(wbase + 256 * 1024);
  f16* bw = (f16*)(wbase + 384 * 1024);

  k_prep <<<16,   256, 0, stream>>>(wq, wk, wv, wf, bq, bk, bv, bw);
  k_lnqkv<<<512,  512, 0, stream>>>(x, g, b, bq, bk, bv, qh, kh, vTh);
  k_attn <<<1024, 512, 0, stream>>>(qh, kh, vTh, ah);
  k_out  <<<512,  512, 0, stream>>>(ah, bw, bf, out);
}